// Round 6
// baseline (372.827 us; speedup 1.0000x reference)
//
#include <hip/hip_runtime.h>

#define BB 128
#define NN 8192
#define SS 100
#define KK 512
#define SPLIT 25                 // sample chunks per batch row
#define SPB (SS / SPLIT)         // samples per block = 4
#define NT 256                   // threads per block (4 waves)
#define EPT 32                   // elements per thread
#define VPT 8                    // float4 loads per thread
#define CAND 512                 // candidate list capacity (threshold bin)
#define NBIN 2048
#define BPT (NBIN / NT)          // bins per thread = 8
#define NWAVE (NT / 64)          // 4

// Linear monotone binning of p into [0,2047]; exactness does not depend on
// the range (clamped bins are handled by exact in-bin ranking).
__device__ __forceinline__ int bin_of(float p) {
    const float SC = 2048.0f / 36.0f;
    const float OF = 12.0f * SC;
    int b = (int)fmaf(p, SC, OF);
    b = b < 0 ? 0 : b;
    return b > 2047 ? 2047 : b;
}

__device__ __forceinline__ float fast_ln(float x) {
    return __builtin_amdgcn_logf(x) * 0.69314718056f;   // v_log_f32 * ln2
}

// Deterministic: same inputs -> bit-identical p everywhere it's computed.
__device__ __forceinline__ float p_of(float u, float lgv) {
    return lgv - fast_ln(-fast_ln(u + 1e-20f) + 1e-20f);
}

// MODE 0: write packed-u8 partial counts to ws. MODE 1: atomicAdd into out.
template <int MODE>
__global__ __launch_bounds__(NT) void gumbel_topk_kernel(
    const float* __restrict__ logits,
    const float* __restrict__ uniform,
    void* __restrict__ sink) {

    __shared__ __align__(16) int hist[NBIN];
    __shared__ float candKey[CAND];
    __shared__ int   candIdx[CAND];
    __shared__ int   waveTot[NWAVE];
    __shared__ int   bcastSel;
    __shared__ int   bcastKK;
    __shared__ int   candCnt;

    const int tid  = threadIdx.x;
    const int lane = tid & 63;
    const int wv   = tid >> 6;
    const int b     = blockIdx.x / SPLIT;
    const int chunk = blockIdx.x % SPLIT;

    const float* lrow = logits + (size_t)b * NN;

    // packed per-element counters: 4 x u8 per register (max count SPB=4)
    unsigned cnt4[EPT / 4];
#pragma unroll
    for (int i = 0; i < EPT / 4; ++i) cnt4[i] = 0;

    // ---- initial histogram zero: 2048 ints / 256 threads
    *reinterpret_cast<int4*>(&hist[tid * 8])     = make_int4(0, 0, 0, 0);
    *reinterpret_cast<int4*>(&hist[tid * 8 + 4]) = make_int4(0, 0, 0, 0);
    __syncthreads();

    const int s0 = chunk * SPB;

    for (int si = 0; si < SPB; ++si) {
        const float* urow = uniform + ((size_t)b * SS + (s0 + si)) * NN;

        // ---- phase 1: stream u + logits, histogram bins; keep ONLY the
        // packed 16-bit bin per element (p is recomputed for rare cases).
        unsigned bpack[EPT / 2];
#pragma unroll
        for (int j = 0; j < VPT; ++j) {
            const float4 uv = *reinterpret_cast<const float4*>(urow + j * 1024 + tid * 4);
            const float4 lv = *reinterpret_cast<const float4*>(lrow + j * 1024 + tid * 4);
            const int b0 = bin_of(p_of(uv.x, lv.x));
            const int b1 = bin_of(p_of(uv.y, lv.y));
            const int b2 = bin_of(p_of(uv.z, lv.z));
            const int b3 = bin_of(p_of(uv.w, lv.w));
            atomicAdd(&hist[b0], 1);
            atomicAdd(&hist[b1], 1);
            atomicAdd(&hist[b2], 1);
            atomicAdd(&hist[b3], 1);
            bpack[j * 2]     = (unsigned)b0 | ((unsigned)b1 << 16);
            bpack[j * 2 + 1] = (unsigned)b2 | ((unsigned)b3 << 16);
        }
        __syncthreads();                                   // s1

        // B1: read own bins, zero them, wave suffix scan
        const int base = tid * BPT;
        int hloc[BPT];
        int sum = 0;
        {
            const int4 h0 = *reinterpret_cast<const int4*>(&hist[base]);
            const int4 h1 = *reinterpret_cast<const int4*>(&hist[base + 4]);
            hloc[0] = h0.x; hloc[1] = h0.y; hloc[2] = h0.z; hloc[3] = h0.w;
            hloc[4] = h1.x; hloc[5] = h1.y; hloc[6] = h1.z; hloc[7] = h1.w;
            const int4 z = make_int4(0, 0, 0, 0);
            *reinterpret_cast<int4*>(&hist[base])     = z;
            *reinterpret_cast<int4*>(&hist[base + 4]) = z;
#pragma unroll
            for (int i = 0; i < BPT; ++i) sum += hloc[i];
        }
        int suf = sum;   // inclusive suffix sum within wave
#pragma unroll
        for (int d = 1; d < 64; d <<= 1) {
            const int o = __shfl_down(suf, d);
            if (lane + d < 64) suf += o;
        }
        if (lane == 0) waveTot[wv] = suf;
        __syncthreads();                                   // s2

        // B2: locate threshold bin, broadcast
        int above = suf - sum;
        for (int w2 = wv + 1; w2 < NWAVE; ++w2) above += waveTot[w2];
        int cum = above;
#pragma unroll
        for (int i = BPT - 1; i >= 0; --i) {
            const int h = hloc[i];
            if (cum < KK && cum + h >= KK) { bcastSel = base + i; bcastKK = KK - cum; }
            cum += h;
        }
        if (tid == 0) candCnt = 0;
        __syncthreads();                                   // s3

        const int selBin = bcastSel;
        const int kk     = bcastKK;

        // C: collect threshold-bin candidates (~10-40 of 8192); recompute p
        // from L2-hot scattered reloads (bit-identical to phase 1).
#pragma unroll
        for (int e = 0; e < EPT; ++e) {
            const int bb = (bpack[e >> 1] >> ((e & 1) * 16)) & 0xFFFF;
            if (bb == selBin) {
                const int gidx = (e >> 2) * 1024 + tid * 4 + (e & 3);
                const float pv = p_of(urow[gidx], lrow[gidx]);
                const int pos = atomicAdd(&candCnt, 1);
                if (pos < CAND) {
                    candKey[pos] = pv;
                    candIdx[pos] = gidx;
                }
            }
        }
        __syncthreads();                                   // s4

        // E: membership; in-bin elements fetch their p from the cand list
        // and rank themselves inline (key desc, index asc = JAX tie-break).
        const int c = candCnt < CAND ? candCnt : CAND;
#pragma unroll
        for (int e = 0; e < EPT; ++e) {
            const int bb = (bpack[e >> 1] >> ((e & 1) * 16)) & 0xFFFF;
            if (bb > selBin) {
                cnt4[e >> 2] += 1u << ((e & 3) * 8);
            } else if (bb == selBin) {
                const int il = (e >> 2) * 1024 + tid * 4 + (e & 3);
                float kl = 0.0f;
                bool found = false;
                for (int j = 0; j < c; ++j) {
                    if (candIdx[j] == il) { kl = candKey[j]; found = true; }
                }
                if (found) {
                    int rank = 0;
                    for (int j = 0; j < c; ++j) {
                        const float kj = candKey[j];
                        rank += (kj > kl || (kj == kl && candIdx[j] < il)) ? 1 : 0;
                    }
                    if (rank < kk) cnt4[e >> 2] += 1u << ((e & 3) * 8);
                }
            }
        }
        // no barrier: next phase-1 touches only hist (quiet since B1); cand
        // arrays are rewritten only after the next s3.
    }

    if (MODE == 0) {
        // coalesced packed-u8 partial counts; dword dn covers gidx [4dn,4dn+3]
        unsigned* wsrow = reinterpret_cast<unsigned*>(sink) + (size_t)blockIdx.x * (NN / 4);
#pragma unroll
        for (int j = 0; j < VPT; ++j) wsrow[j * NT + tid] = cnt4[j];
    } else {
        float* orow = reinterpret_cast<float*>(sink) + (size_t)b * NN;
#pragma unroll
        for (int e = 0; e < EPT; ++e) {
            const unsigned cc = (cnt4[e >> 2] >> ((e & 3) * 8)) & 0xFFu;
            if (cc) {
                const int gidx = (e >> 2) * 1024 + tid * 4 + (e & 3);
                atomicAdd(orow + gidx, (float)cc * 0.01f);
            }
        }
    }
}

// Sum SPLIT packed-u8 partials per dword (max 4*25=100 per byte: no carry),
// scale by 0.01, write float4. One thread per output dword-group.
__global__ __launch_bounds__(256) void reduce_kernel(
    const unsigned* __restrict__ ws, float* __restrict__ out) {
    const int d  = blockIdx.x * 256 + threadIdx.x;   // dword id, 0..262143
    const int b  = d >> 11;
    const int dn = d & 2047;
    unsigned acc = 0;
#pragma unroll
    for (int ch = 0; ch < SPLIT; ++ch)
        acc += ws[((size_t)(b * SPLIT + ch) << 11) + dn];
    float4 o;
    o.x = (float)(acc & 255u) * 0.01f;
    o.y = (float)((acc >> 8) & 255u) * 0.01f;
    o.z = (float)((acc >> 16) & 255u) * 0.01f;
    o.w = (float)(acc >> 24) * 0.01f;
    *reinterpret_cast<float4*>(out + ((size_t)d << 2)) = o;
}

extern "C" void kernel_launch(void* const* d_in, const int* in_sizes, int n_in,
                              void* d_out, int out_size, void* d_ws, size_t ws_size,
                              hipStream_t stream) {
    const float* logits  = (const float*)d_in[0];   // [128, 8192] f32
    const float* uniform = (const float*)d_in[1];   // [128, 100, 8192] f32
    float* out = (float*)d_out;                     // [128, 8192] f32

    const int grid = BB * SPLIT;                    // 3200 blocks
    const size_t need = (size_t)grid * NN;          // 26.2 MB of u8 partials

    if (ws_size >= need) {
        gumbel_topk_kernel<0><<<grid, NT, 0, stream>>>(logits, uniform, d_ws);
        reduce_kernel<<<(BB * NN / 4) / 256, 256, 0, stream>>>(
            (const unsigned*)d_ws, out);
    } else {
        hipMemsetAsync(out, 0, (size_t)out_size * sizeof(float), stream);
        gumbel_topk_kernel<1><<<grid, NT, 0, stream>>>(logits, uniform, d_out);
    }
}

// Round 7
// 159.168 us; speedup vs baseline: 2.3423x; 2.3423x over previous
//
#include <hip/hip_runtime.h>

#define BB 128
#define NN 8192
#define SS 100
#define KK 512
#define SPLIT 20                 // sample chunks per batch row
#define SPB (SS / SPLIT)         // samples per block = 5
#define NT 1024                  // threads per block (16 waves)
#define EPT 8                    // elements per thread
#define VPT 2                    // float4 loads per thread
#define CAND 256                 // candidate list capacity (threshold bin)
#define NBIN 2048
#define BPT (NBIN / NT)          // bins per thread = 2
#define NWAVE (NT / 64)          // 16

#define GIDX(e) (((e) >> 2) * 4096 + tid * 4 + ((e) & 3))

// Level-1 map: [2,23] -> bins 1..2047; bin 0 = "below floor" catch-all.
// Threshold for K=512/8192 sits at p ~ 3.3 (22+ sigma above the floor), so
// ~85% of elements skip the histogram entirely; bin-0 count is implied.
__device__ __forceinline__ int binL1(float p) {
    const float SC = 2047.0f / 21.0f;
    const float OF = 1.0f - 2.0f * SC;
    int b = (int)fmaf(p, SC, OF);
    b = b < 0 ? 0 : b;
    return b > 2047 ? 2047 : b;
}
// Level-2 map: [-12,2] -> 0..2047. Used only if the catch-all is selected
// (never on this data, but keeps the kernel exact for any input).
__device__ __forceinline__ int binL2(float p) {
    const float SC = 2048.0f / 14.0f;
    const float OF = 12.0f * SC;
    int b = (int)fmaf(p, SC, OF);
    b = b < 0 ? 0 : b;
    return b > 2047 ? 2047 : b;
}

__device__ __forceinline__ float fast_ln(float x) {
    return __builtin_amdgcn_logf(x) * 0.69314718056f;   // v_log_f32 * ln2
}
// Deterministic: bit-identical p everywhere it's computed.
__device__ __forceinline__ float p_of(float u, float lgv) {
    return lgv - fast_ln(-fast_ln(u + 1e-20f) + 1e-20f);
}

// MODE 0: write packed-u8 partial counts to ws. MODE 1: atomicAdd into out.
template <int MODE>
__global__ __launch_bounds__(NT, 8) void gumbel_topk_kernel(
    const float* __restrict__ logits,
    const float* __restrict__ uniform,
    void* __restrict__ sink) {

    __shared__ __align__(16) int hist[NBIN];
    __shared__ float candKey[CAND];
    __shared__ int   candIdx[CAND];
    __shared__ int   waveTot[NWAVE];
    __shared__ int   bcastSel;
    __shared__ int   bcastKK;
    __shared__ int   candCnt;

    const int tid  = threadIdx.x;
    const int lane = tid & 63;
    const int wv   = tid >> 6;
    const int b     = blockIdx.x / SPLIT;
    const int chunk = blockIdx.x % SPLIT;

    const float* lrow = logits + (size_t)b * NN;
    const int s0 = chunk * SPB;

    // ---- logits chunk into registers (reused across samples)
    float lg[EPT];
#pragma unroll
    for (int j = 0; j < VPT; ++j) {
        const float4 v = *reinterpret_cast<const float4*>(lrow + j * 4096 + tid * 4);
        lg[j * 4 + 0] = v.x; lg[j * 4 + 1] = v.y;
        lg[j * 4 + 2] = v.z; lg[j * 4 + 3] = v.w;
    }

    auto loadSample = [&](float (&dst)[EPT], int s) {
        const float* urow = uniform + ((size_t)b * SS + s) * NN;
#pragma unroll
        for (int j = 0; j < VPT; ++j) {
            const float4 v = *reinterpret_cast<const float4*>(urow + j * 4096 + tid * 4);
            dst[j * 4 + 0] = v.x; dst[j * 4 + 1] = v.y;
            dst[j * 4 + 2] = v.z; dst[j * 4 + 3] = v.w;
        }
    };

    float bufA[EPT], bufB[EPT];
    loadSample(bufA, s0 + 0);       // in flight during init
    loadSample(bufB, s0 + 1);

    unsigned cnt4[EPT / 4];         // 4 x u8 per reg (max count SPB=5)
#pragma unroll
    for (int i = 0; i < EPT / 4; ++i) cnt4[i] = 0;

    *reinterpret_cast<int2*>(&hist[tid * 2]) = make_int2(0, 0);
    __syncthreads();

    // Scan hist (suffix, high->low), zero it, select bin holding the
    // Ktarget-th largest; fallback to catch-all bin 0 if count < Ktarget.
    // Results in bcastSel/bcastKK; also resets candCnt. 2 barriers.
    auto scanSelect = [&](int Ktarget) {
        const int base = tid * BPT;
        const int2 h = *reinterpret_cast<const int2*>(&hist[base]);
        *reinterpret_cast<int2*>(&hist[base]) = make_int2(0, 0);
        const int hlo = h.x, hhi = h.y;
        const int sum = hlo + hhi;
        int suf = sum;   // inclusive suffix sum within wave
#pragma unroll
        for (int d = 1; d < 64; d <<= 1) {
            const int o = __shfl_down(suf, d);
            if (lane + d < 64) suf += o;
        }
        if (lane == 0) waveTot[wv] = suf;
        __syncthreads();                               // sA
        int cum = suf - sum;                           // strictly above my bins
        for (int w2 = wv + 1; w2 < NWAVE; ++w2) cum += waveTot[w2];
        if (cum < Ktarget && cum + hhi >= Ktarget) { bcastSel = base + 1; bcastKK = Ktarget - cum; }
        cum += hhi;
        if (cum < Ktarget && cum + hlo >= Ktarget) { bcastSel = base;     bcastKK = Ktarget - cum; }
        cum += hlo;
        if (tid == 0) {
            candCnt = 0;
            if (cum < Ktarget) { bcastSel = 0; bcastKK = Ktarget - cum; }  // catch-all
        }
        __syncthreads();                               // sB
    };

    auto processSample = [&](float (&cur)[EPT]) {
        // p = logit + gumbel in place; histogram only above-floor elements
        unsigned act = 0;
#pragma unroll
        for (int e = 0; e < EPT; ++e) {
            cur[e] = p_of(cur[e], lg[e]);
            const int bb = binL1(cur[e]);
            if (bb > 0) { act |= (1u << e); atomicAdd(&hist[bb], 1); }
        }
        __syncthreads();                               // s1
        scanSelect(KK);
        const int selBin = bcastSel;
        const int kk     = bcastKK;

        if (selBin > 0) {
            // hot path: collect threshold-bin candidates (~6 expected)
#pragma unroll
            for (int e = 0; e < EPT; ++e) {
                if (((act >> e) & 1) && binL1(cur[e]) == selBin) {
                    const int pos = atomicAdd(&candCnt, 1);
                    if (pos < CAND) { candKey[pos] = cur[e]; candIdx[pos] = GIDX(e); }
                }
            }
            __syncthreads();                           // s4
            const int c = candCnt < CAND ? candCnt : CAND;
#pragma unroll
            for (int e = 0; e < EPT; ++e) {
                if ((act >> e) & 1) {
                    const int bb = binL1(cur[e]);
                    if (bb > selBin) {
                        cnt4[e >> 2] += 1u << ((e & 3) * 8);
                    } else if (bb == selBin) {
                        const float kl = cur[e];
                        const int   il = GIDX(e);
                        int rank = 0;
                        for (int j = 0; j < c; ++j)
                            rank += (candKey[j] > kl ||
                                     (candKey[j] == kl && candIdx[j] < il)) ? 1 : 0;
                        if (rank < kk) cnt4[e >> 2] += 1u << ((e & 3) * 8);
                    }
                }
            }
        } else {
            // cold path (exactness safety net; never taken on this data):
            // all above-floor elements are in; refine below-floor by level-2.
#pragma unroll
            for (int e = 0; e < EPT; ++e)
                if (!((act >> e) & 1)) atomicAdd(&hist[binL2(cur[e])], 1);
            __syncthreads();
            scanSelect(kk);
            const int selBin2 = bcastSel;
            const int kk2     = bcastKK;
#pragma unroll
            for (int e = 0; e < EPT; ++e) {
                if (!((act >> e) & 1) && binL2(cur[e]) == selBin2) {
                    const int pos = atomicAdd(&candCnt, 1);
                    if (pos < CAND) { candKey[pos] = cur[e]; candIdx[pos] = GIDX(e); }
                }
            }
            __syncthreads();
            const int c = candCnt < CAND ? candCnt : CAND;
#pragma unroll
            for (int e = 0; e < EPT; ++e) {
                if ((act >> e) & 1) {
                    cnt4[e >> 2] += 1u << ((e & 3) * 8);
                } else {
                    const int b2 = binL2(cur[e]);
                    if (b2 > selBin2) {
                        cnt4[e >> 2] += 1u << ((e & 3) * 8);
                    } else if (b2 == selBin2) {
                        const float kl = cur[e];
                        const int   il = GIDX(e);
                        int rank = 0;
                        for (int j = 0; j < c; ++j)
                            rank += (candKey[j] > kl ||
                                     (candKey[j] == kl && candIdx[j] < il)) ? 1 : 0;
                        if (rank < kk2) cnt4[e >> 2] += 1u << ((e & 3) * 8);
                    }
                }
            }
        }
        // no trailing barrier: next phase touches hist only after s1, and
        // cand arrays are rewritten only after the next scanSelect.
    };

    // dbuf schedule: next sample's loads in flight during current processing
    processSample(bufA); loadSample(bufA, s0 + 2);
    processSample(bufB); loadSample(bufB, s0 + 3);
    processSample(bufA); loadSample(bufA, s0 + 4);
    processSample(bufB);
    processSample(bufA);

    if (MODE == 0) {
        // coalesced packed-u8 partial counts; dword dn covers gidx [4dn,4dn+3]
        unsigned* wsrow = reinterpret_cast<unsigned*>(sink) + (size_t)blockIdx.x * (NN / 4);
#pragma unroll
        for (int j = 0; j < VPT; ++j) wsrow[j * NT + tid] = cnt4[j];
    } else {
        float* orow = reinterpret_cast<float*>(sink) + (size_t)b * NN;
#pragma unroll
        for (int e = 0; e < EPT; ++e) {
            const unsigned cc = (cnt4[e >> 2] >> ((e & 3) * 8)) & 0xFFu;
            if (cc) atomicAdd(orow + GIDX(e), (float)cc * 0.01f);
        }
    }
}

// Sum SPLIT packed-u8 partials per dword (max 5*20=100 per byte: no carry),
// scale by 0.01, write float4. One thread per output dword-group.
__global__ __launch_bounds__(256) void reduce_kernel(
    const unsigned* __restrict__ ws, float* __restrict__ out) {
    const int d  = blockIdx.x * 256 + threadIdx.x;   // dword id, 0..262143
    const int b  = d >> 11;
    const int dn = d & 2047;
    unsigned acc = 0;
#pragma unroll
    for (int ch = 0; ch < SPLIT; ++ch)
        acc += ws[((size_t)(b * SPLIT + ch) << 11) + dn];
    float4 o;
    o.x = (float)(acc & 255u) * 0.01f;
    o.y = (float)((acc >> 8) & 255u) * 0.01f;
    o.z = (float)((acc >> 16) & 255u) * 0.01f;
    o.w = (float)(acc >> 24) * 0.01f;
    *reinterpret_cast<float4*>(out + ((size_t)d << 2)) = o;
}

extern "C" void kernel_launch(void* const* d_in, const int* in_sizes, int n_in,
                              void* d_out, int out_size, void* d_ws, size_t ws_size,
                              hipStream_t stream) {
    const float* logits  = (const float*)d_in[0];   // [128, 8192] f32
    const float* uniform = (const float*)d_in[1];   // [128, 100, 8192] f32
    float* out = (float*)d_out;                     // [128, 8192] f32

    const int grid = BB * SPLIT;                    // 2560 blocks
    const size_t need = (size_t)grid * NN;          // 21 MB of u8 partials

    if (ws_size >= need) {
        gumbel_topk_kernel<0><<<grid, NT, 0, stream>>>(logits, uniform, d_ws);
        reduce_kernel<<<(BB * NN / 4) / 256, 256, 0, stream>>>(
            (const unsigned*)d_ws, out);
    } else {
        hipMemsetAsync(out, 0, (size_t)out_size * sizeof(float), stream);
        gumbel_topk_kernel<1><<<grid, NT, 0, stream>>>(logits, uniform, d_out);
    }
}